// Round 4
// baseline (15412.064 us; speedup 1.0000x reference)
//
#include <hip/hip_runtime.h>
#include <hip/hip_bf16.h>
#include <math.h>

typedef __hip_bfloat16 bf16;

#define B_    4
#define NQ_   512
#define NC_   2048
#define DQ_   1024
#define DC_   768
#define C_    1024
#define H_    16
#define HD_   64
#define EPS_  1e-5f

// ---- runtime-dtyped load of EXTERNAL tensors (flag: 1=fp32, 0=bf16) ----
__device__ __forceinline__ float ldin(const void* p, size_t i, int f32) {
    return f32 ? ((const float*)p)[i]
               : __bfloat162float(((const bf16*)p)[i]);
}
__device__ __forceinline__ float ldb(const bf16* p, size_t i) {
    return __bfloat162float(p[i]);
}

// ---------------------------------------------------------------------------
// dtype sniffer: for bf16 data the low 16 bits of each dword are a full bf16
// (exponent field in [0x70,0x82] ~always for N(0,1) data); for fp32 data they
// are mantissa tail (~7% hit rate). Writes flag[0] = (fp32 ? 1 : 0).
// ---------------------------------------------------------------------------
__global__ __launch_bounds__(256)
void sniff_k(const void* __restrict__ q, int* __restrict__ flag)
{
    __shared__ int red[256];
    const unsigned* w = (const unsigned*)q;
    const int t = threadIdx.x;
    int cnt = 0;
    for (int i = t; i < 1024; i += 256) {
        unsigned e = (w[i] >> 7) & 0xFFu;
        cnt += (e >= 0x70u && e <= 0x82u) ? 1 : 0;
    }
    red[t] = cnt; __syncthreads();
    for (int s = 128; s > 0; s >>= 1) { if (t < s) red[t] += red[t + s]; __syncthreads(); }
    if (t == 0) flag[0] = (red[0] > 512) ? 0 : 1;
}

// ---------------------------------------------------------------------------
// Generic GEMM: out[M,N] = act(A[M,K+aoff..] @ W[woff..][K,N] + bias[boff..])
// AEXT: A external (runtime dtype) else bf16 ws. W/bias external, with
// ELEMENT offsets woff/boff (dtype width applied on device).
// ---------------------------------------------------------------------------
template<int ACT, int ACC, int AEXT, typename TO>
__global__ __launch_bounds__(256)
void gemm_k(const void* __restrict__ A, size_t aoff,
            const void* __restrict__ W, size_t woff,
            const void* __restrict__ bias, size_t boff,
            TO* __restrict__ out, int M, int N, int K,
            const int* __restrict__ dtf)
{
    __shared__ float As[64][17];
    __shared__ float Bs[16][64];
    const int f32 = dtf[0];
    const int t  = threadIdx.x;
    const int tx = t & 15, ty = t >> 4;
    const int row0 = blockIdx.y * 64;
    const int col0 = blockIdx.x * 64;
    float acc[4][4] = {};
    for (int k0 = 0; k0 < K; k0 += 16) {
#pragma unroll
        for (int i = 0; i < 4; i++) {
            int idx = t + 256 * i;
            int kk = idx & 15, mm = idx >> 4;
            size_t gi = aoff + (size_t)(row0 + mm) * K + k0 + kk;
            As[mm][kk] = AEXT ? ldin(A, gi, f32) : ldb((const bf16*)A, gi);
        }
#pragma unroll
        for (int i = 0; i < 4; i++) {
            int idx = t + 256 * i;
            int nn = idx & 63, kk = idx >> 6;
            Bs[kk][nn] = ldin(W, woff + (size_t)(k0 + kk) * N + col0 + nn, f32);
        }
        __syncthreads();
#pragma unroll
        for (int kk = 0; kk < 16; kk++) {
            float a[4], b[4];
#pragma unroll
            for (int i = 0; i < 4; i++) a[i] = As[ty * 4 + i][kk];
#pragma unroll
            for (int j = 0; j < 4; j++) b[j] = Bs[kk][tx * 4 + j];
#pragma unroll
            for (int i = 0; i < 4; i++)
#pragma unroll
                for (int j = 0; j < 4; j++)
                    acc[i][j] = fmaf(a[i], b[j], acc[i][j]);
        }
        __syncthreads();
    }
#pragma unroll
    for (int i = 0; i < 4; i++) {
        int r = row0 + ty * 4 + i;
#pragma unroll
        for (int j = 0; j < 4; j++) {
            int cc = col0 + tx * 4 + j;
            float v = acc[i][j] + ldin(bias, boff + cc, f32);
            if (ACT == 1) v = 0.5f * v * (1.0f + erff(v * 0.70710678118654752440f));
            size_t o = (size_t)r * N + cc;
            if constexpr (ACC) { out[o] += v; }
            else if constexpr (sizeof(TO) == 4) { out[o] = (TO)v; }
            else { ((bf16*)out)[o] = __float2bfloat16(v); }
        }
    }
}

// ---------------------------------------------------------------------------
// LayerNorm (C_=1024). x fp32 ws. g/b external with element offset.
// OFINAL: store to d_out in runtime dtype; else bf16 ws.
// ---------------------------------------------------------------------------
template<int OFINAL>
__global__ __launch_bounds__(256)
void ln_k(const float* __restrict__ x, const void* __restrict__ g,
          const void* __restrict__ b, size_t gboff, void* __restrict__ out,
          const int* __restrict__ dtf)
{
    __shared__ float red[256];
    const int f32 = dtf[0];
    const int row = blockIdx.x;
    const int t = threadIdx.x;
    const float* xr = x + (size_t)row * C_;
    float v[4];
#pragma unroll
    for (int i = 0; i < 4; i++) v[i] = xr[t + 256 * i];
    float s = v[0] + v[1] + v[2] + v[3];
    red[t] = s; __syncthreads();
    for (int st = 128; st > 0; st >>= 1) { if (t < st) red[t] += red[t + st]; __syncthreads(); }
    float mean = red[0] * (1.0f / C_);
    __syncthreads();
    float s2 = 0.f;
#pragma unroll
    for (int i = 0; i < 4; i++) { float d = v[i] - mean; s2 += d * d; }
    red[t] = s2; __syncthreads();
    for (int st = 128; st > 0; st >>= 1) { if (t < st) red[t] += red[t + st]; __syncthreads(); }
    float rstd = rsqrtf(red[0] * (1.0f / C_) + EPS_);
#pragma unroll
    for (int i = 0; i < 4; i++) {
        int cc = t + 256 * i;
        float r = (v[i] - mean) * rstd * ldin(g, gboff + cc, f32) + ldin(b, gboff + cc, f32);
        size_t o = (size_t)row * C_ + cc;
        if constexpr (OFINAL) {
            if (f32) ((float*)out)[o] = r; else ((bf16*)out)[o] = __float2bfloat16(r);
        } else {
            ((bf16*)out)[o] = __float2bfloat16(r);
        }
    }
}

// ---------------------------------------------------------------------------
// Attention for ONE batch element. One block per (h,q) row.
// ---------------------------------------------------------------------------
__global__ __launch_bounds__(256)
void attn_k(const bf16* __restrict__ qh, const bf16* __restrict__ kv,
            const int* __restrict__ mask, bf16* __restrict__ out)
{
    __shared__ float qrow[HD_];
    __shared__ float sc[NC_];
    __shared__ float red[256];
    __shared__ float psum[4][HD_];
    const int h  = blockIdx.x / NQ_;
    const int qi = blockIdx.x % NQ_;
    const int t  = threadIdx.x;

    const bf16* qptr = qh + (size_t)qi * C_ + h * HD_;
    if (t < HD_) qrow[t] = ldb(qptr, t);
    __syncthreads();

    const float scale = 0.125f;  // 1/sqrt(64)
    const bf16* kbase = kv + h * HD_;

    float lmax = -INFINITY;
    for (int n = t; n < NC_; n += 256) {
        const bf16* kr = kbase + (size_t)n * (2 * C_);
        float d = 0.f;
#pragma unroll
        for (int j = 0; j < HD_; j++) d = fmaf(qrow[j], ldb(kr, j), d);
        float s = (mask[n] == 0) ? -INFINITY : d * scale;
        sc[n] = s;
        lmax = fmaxf(lmax, s);
    }
    red[t] = lmax; __syncthreads();
    for (int st = 128; st > 0; st >>= 1) { if (t < st) red[t] = fmaxf(red[t], red[t + st]); __syncthreads(); }
    float mx = red[0];
    __syncthreads();

    float lsum = 0.f;
    for (int n = t; n < NC_; n += 256) {
        float e = expf(sc[n] - mx);
        sc[n] = e;
        lsum += e;
    }
    red[t] = lsum; __syncthreads();
    for (int st = 128; st > 0; st >>= 1) { if (t < st) red[t] += red[t + st]; __syncthreads(); }
    float inv = 1.0f / red[0];
    __syncthreads();

    const int d = t & (HD_ - 1);
    const int c = t >> 6;
    const bf16* vbase = kv + C_ + h * HD_;
    float part = 0.f;
    for (int n = c; n < NC_; n += 4)
        part = fmaf(sc[n], ldb(vbase, (size_t)n * (2 * C_) + d), part);
    psum[c][d] = part;
    __syncthreads();
    if (t < HD_) {
        float o = (psum[0][t] + psum[1][t] + psum[2][t] + psum[3][t]) * inv;
        out[(size_t)qi * C_ + h * HD_ + t] = __float2bfloat16(o);
    }
}

// ---------------------------------------------------------------------------
extern "C" void kernel_launch(void* const* d_in, const int* in_sizes, int n_in,
                              void* d_out, int out_size, void* d_ws, size_t ws_size,
                              hipStream_t stream)
{
    const void* query   = d_in[0];
    const void* context = d_in[1];
    const int*  mask    = (const int*)d_in[2];
    const void* Wqp = d_in[3];  const void* bqp  = d_in[4];
    const void* Wcp = d_in[5];  const void* bcp  = d_in[6];
    const void* Wq  = d_in[7];  const void* bq   = d_in[8];
    const void* Wkv = d_in[9];  const void* bkv  = d_in[10];
    const void* Wo  = d_in[11]; const void* bo   = d_in[12];
    const void* g1  = d_in[13]; const void* be1  = d_in[14];
    const void* W1  = d_in[15]; const void* bf1  = d_in[16];
    const void* W2  = d_in[17]; const void* bf2  = d_in[18];
    const void* g2  = d_in[19]; const void* be2  = d_in[20];
    const void* gf  = d_in[21]; const void* bef  = d_in[22];

    // workspace — peak 28 MB + 4 B flag
    char* w = (char*)d_ws;
    float* q   = (float*)(w);                 // [2048,1024] f32  8 MB @ 0
    bf16*  xn  = (bf16*) (w + ( 8u << 20));   // [2048,1024] bf16 4 MB @ 8
    bf16*  cb  = (bf16*) (w + ( 8u << 20));   // aliases xn (attention phase)
    bf16*  qh  = (bf16*) (w + (12u << 20));   // 4 MB @ 12
    bf16*  ao  = (bf16*) (w + (16u << 20));   // 4 MB @ 16
    bf16*  kvb = (bf16*) (w + (20u << 20));   // [2048,2048] bf16 8 MB @ 20
    bf16*  ff1 = (bf16*) (w + (12u << 20));   // [2048,4096] bf16 16 MB @ 12 (alias)
    int*   dtf = (int*)  (w + (28u << 20));   // dtype flag

    const int MQ = B_ * NQ_;   // 2048
    dim3 blk(256);

    sniff_k<<<1, blk, 0, stream>>>(query, dtf);

    // query projection: q = query @ Wqp + bqp   (f32 out)
    gemm_k<0,0,1><<<dim3(C_/64, MQ/64), blk, 0, stream>>>(
        query, 0, Wqp, 0, bqp, 0, q, MQ, C_, DQ_, dtf);

    for (int l = 0; l < 2; l++) {
        const size_t oC  = (size_t)l * C_;
        const size_t oCC = (size_t)l * C_ * C_;
        const size_t o2C = (size_t)l * 2 * C_;
        const size_t oK2 = (size_t)l * C_ * 2 * C_;
        const size_t o4C = (size_t)l * 4 * C_;
        const size_t oK4 = (size_t)l * C_ * 4 * C_;

        ln_k<0><<<MQ, blk, 0, stream>>>(q, g1, be1, oC, xn, dtf);
        gemm_k<0,0,0><<<dim3(C_/64, MQ/64), blk, 0, stream>>>(
            xn, 0, Wq, oCC, bq, oC, qh, MQ, C_, C_, dtf);

        for (int b = 0; b < B_; b++) {
            // context projection for this batch (cb aliases xn — xn is dead here)
            gemm_k<0,0,1><<<dim3(C_/64, NC_/64), blk, 0, stream>>>(
                context, (size_t)b * NC_ * DC_, Wcp, 0, bcp, 0, cb, NC_, C_, DC_, dtf);
            gemm_k<0,0,0><<<dim3(2*C_/64, NC_/64), blk, 0, stream>>>(
                cb, 0, Wkv, oK2, bkv, o2C, kvb, NC_, 2*C_, C_, dtf);
            attn_k<<<H_ * NQ_, blk, 0, stream>>>(qh + (size_t)b * NQ_ * C_, kvb,
                                                 mask + b * NC_, ao + (size_t)b * NQ_ * C_);
        }

        gemm_k<0,1,0><<<dim3(C_/64, MQ/64), blk, 0, stream>>>(
            ao, 0, Wo, oCC, bo, oC, q, MQ, C_, C_, dtf);
        ln_k<0><<<MQ, blk, 0, stream>>>(q, g2, be2, oC, xn, dtf);
        gemm_k<1,0,0><<<dim3(4*C_/64, MQ/64), blk, 0, stream>>>(
            xn, 0, W1, oK4, bf1, o4C, ff1, MQ, 4*C_, C_, dtf);
        gemm_k<0,1,0><<<dim3(C_/64, MQ/64), blk, 0, stream>>>(
            ff1, 0, W2, oK4, bf2, oC, q, MQ, C_, 4*C_, dtf);
    }

    ln_k<1><<<MQ, blk, 0, stream>>>(q, gf, bef, 0, d_out, dtf);
}

// Round 5
// 6754.897 us; speedup vs baseline: 2.2816x; 2.2816x over previous
//
#include <hip/hip_runtime.h>
#include <hip/hip_bf16.h>
#include <math.h>

typedef __hip_bfloat16 bf16;

#define B_    4
#define NQ_   512
#define NC_   2048
#define DQ_   1024
#define DC_   768
#define C_    1024
#define H_    16
#define HD_   64
#define EPS_  1e-5f

// ---- runtime-dtyped load of EXTERNAL tensors (flag: 1=fp32, 0=bf16) ----
__device__ __forceinline__ float ldin(const void* p, size_t i, int f32) {
    return f32 ? ((const float*)p)[i]
               : __bfloat162float(((const bf16*)p)[i]);
}
__device__ __forceinline__ float ldb(const bf16* p, size_t i) {
    return __bfloat162float(p[i]);
}
// unpack 8 bf16 (as uint4) -> 8 fp32
__device__ __forceinline__ void unpack8(uint4 w, float* f) {
    f[0] = __uint_as_float((w.x & 0xffffu) << 16);
    f[1] = __uint_as_float(w.x & 0xffff0000u);
    f[2] = __uint_as_float((w.y & 0xffffu) << 16);
    f[3] = __uint_as_float(w.y & 0xffff0000u);
    f[4] = __uint_as_float((w.z & 0xffffu) << 16);
    f[5] = __uint_as_float(w.z & 0xffff0000u);
    f[6] = __uint_as_float((w.w & 0xffffu) << 16);
    f[7] = __uint_as_float(w.w & 0xffff0000u);
}

// ---------------------------------------------------------------------------
// dtype sniffer (see round 3): flag[0] = (fp32 ? 1 : 0).
// ---------------------------------------------------------------------------
__global__ __launch_bounds__(256)
void sniff_k(const void* __restrict__ q, int* __restrict__ flag)
{
    __shared__ int red[256];
    const unsigned* w = (const unsigned*)q;
    const int t = threadIdx.x;
    int cnt = 0;
    for (int i = t; i < 1024; i += 256) {
        unsigned e = (w[i] >> 7) & 0xFFu;
        cnt += (e >= 0x70u && e <= 0x82u) ? 1 : 0;
    }
    red[t] = cnt; __syncthreads();
    for (int s = 128; s > 0; s >>= 1) { if (t < s) red[t] += red[t + s]; __syncthreads(); }
    if (t == 0) flag[0] = (red[0] > 512) ? 0 : 1;
}

// ---------------------------------------------------------------------------
// Generic GEMM (unchanged from round 3, correctness-proven).
// ---------------------------------------------------------------------------
template<int ACT, int ACC, int AEXT, typename TO>
__global__ __launch_bounds__(256)
void gemm_k(const void* __restrict__ A, size_t aoff,
            const void* __restrict__ W, size_t woff,
            const void* __restrict__ bias, size_t boff,
            TO* __restrict__ out, int M, int N, int K,
            const int* __restrict__ dtf)
{
    __shared__ float As[64][17];
    __shared__ float Bs[16][64];
    const int f32 = dtf[0];
    const int t  = threadIdx.x;
    const int tx = t & 15, ty = t >> 4;
    const int row0 = blockIdx.y * 64;
    const int col0 = blockIdx.x * 64;
    float acc[4][4] = {};
    for (int k0 = 0; k0 < K; k0 += 16) {
#pragma unroll
        for (int i = 0; i < 4; i++) {
            int idx = t + 256 * i;
            int kk = idx & 15, mm = idx >> 4;
            size_t gi = aoff + (size_t)(row0 + mm) * K + k0 + kk;
            As[mm][kk] = AEXT ? ldin(A, gi, f32) : ldb((const bf16*)A, gi);
        }
#pragma unroll
        for (int i = 0; i < 4; i++) {
            int idx = t + 256 * i;
            int nn = idx & 63, kk = idx >> 6;
            Bs[kk][nn] = ldin(W, woff + (size_t)(k0 + kk) * N + col0 + nn, f32);
        }
        __syncthreads();
#pragma unroll
        for (int kk = 0; kk < 16; kk++) {
            float a[4], b[4];
#pragma unroll
            for (int i = 0; i < 4; i++) a[i] = As[ty * 4 + i][kk];
#pragma unroll
            for (int j = 0; j < 4; j++) b[j] = Bs[kk][tx * 4 + j];
#pragma unroll
            for (int i = 0; i < 4; i++)
#pragma unroll
                for (int j = 0; j < 4; j++)
                    acc[i][j] = fmaf(a[i], b[j], acc[i][j]);
        }
        __syncthreads();
    }
#pragma unroll
    for (int i = 0; i < 4; i++) {
        int r = row0 + ty * 4 + i;
#pragma unroll
        for (int j = 0; j < 4; j++) {
            int cc = col0 + tx * 4 + j;
            float v = acc[i][j] + ldin(bias, boff + cc, f32);
            if (ACT == 1) v = 0.5f * v * (1.0f + erff(v * 0.70710678118654752440f));
            size_t o = (size_t)r * N + cc;
            if constexpr (ACC) { out[o] += v; }
            else if constexpr (sizeof(TO) == 4) { out[o] = (TO)v; }
            else { ((bf16*)out)[o] = __float2bfloat16(v); }
        }
    }
}

// ---------------------------------------------------------------------------
// LayerNorm (unchanged).
// ---------------------------------------------------------------------------
template<int OFINAL>
__global__ __launch_bounds__(256)
void ln_k(const float* __restrict__ x, const void* __restrict__ g,
          const void* __restrict__ b, size_t gboff, void* __restrict__ out,
          const int* __restrict__ dtf)
{
    __shared__ float red[256];
    const int f32 = dtf[0];
    const int row = blockIdx.x;
    const int t = threadIdx.x;
    const float* xr = x + (size_t)row * C_;
    float v[4];
#pragma unroll
    for (int i = 0; i < 4; i++) v[i] = xr[t + 256 * i];
    float s = v[0] + v[1] + v[2] + v[3];
    red[t] = s; __syncthreads();
    for (int st = 128; st > 0; st >>= 1) { if (t < st) red[t] += red[t + st]; __syncthreads(); }
    float mean = red[0] * (1.0f / C_);
    __syncthreads();
    float s2 = 0.f;
#pragma unroll
    for (int i = 0; i < 4; i++) { float d = v[i] - mean; s2 += d * d; }
    red[t] = s2; __syncthreads();
    for (int st = 128; st > 0; st >>= 1) { if (t < st) red[t] += red[t + st]; __syncthreads(); }
    float rstd = rsqrtf(red[0] * (1.0f / C_) + EPS_);
#pragma unroll
    for (int i = 0; i < 4; i++) {
        int cc = t + 256 * i;
        float r = (v[i] - mean) * rstd * ldin(g, gboff + cc, f32) + ldin(b, gboff + cc, f32);
        size_t o = (size_t)row * C_ + cc;
        if constexpr (OFINAL) {
            if (f32) ((float*)out)[o] = r; else ((bf16*)out)[o] = __float2bfloat16(r);
        } else {
            ((bf16*)out)[o] = __float2bfloat16(r);
        }
    }
}

// ---------------------------------------------------------------------------
// Flash attention for ONE batch element.
// Block = 256 threads = one (head, 64-query tile). Grid = H_ * (NQ_/64) = 128.
// qh: [NQ,C] bf16, kv: [NC,2C] bf16 (K cols h*64.., V cols 1024+h*64..),
// out: [NQ,C] bf16.
// LDS: Qs/Ks [d][q|k] transposed (float4 fragment reads), Vs/Ps natural.
// Online softmax with -1e30 masking (no inf/NaN paths).
// ---------------------------------------------------------------------------
__global__ __launch_bounds__(256)
void attn_flash(const bf16* __restrict__ qh, const bf16* __restrict__ kv,
                const int* __restrict__ mask, bf16* __restrict__ out)
{
    __shared__ float Qs[64][68];   // [d][q]
    __shared__ float Ks[64][68];   // [d][k]
    __shared__ float Vs[64][68];   // [k][d]
    __shared__ float Ps[64][68];   // [k][q]
    const int h  = blockIdx.x >> 3;
    const int q0 = (blockIdx.x & 7) * 64;
    const int t  = threadIdx.x;
    const int tx = t & 15, ty = t >> 4;

    // --- load Q tile (transposed into Qs[d][q]) ---
    {
        const int qr = t >> 2, d0 = (t & 3) * 16;
        const bf16* src = qh + (size_t)(q0 + qr) * C_ + h * HD_ + d0;
        float f[8];
#pragma unroll
        for (int u = 0; u < 2; u++) {
            uint4 w = *(const uint4*)(src + u * 8);
            unpack8(w, f);
#pragma unroll
            for (int v = 0; v < 8; v++) Qs[d0 + u * 8 + v][qr] = f[v];
        }
    }

    float o_acc[4][4] = {};
    float m_run[4], l_run[4];
#pragma unroll
    for (int i = 0; i < 4; i++) { m_run[i] = -1e30f; l_run[i] = 0.f; }

    const float scale = 0.125f;  // 1/sqrt(64)

    for (int k0 = 0; k0 < NC_; k0 += 64) {
        // --- global loads for K/V tile (before barrier; no LDS touch yet) ---
        const int kr = t >> 2, d0 = (t & 3) * 16;
        uint4 wk0 = *(const uint4*)(kv + (size_t)(k0 + kr) * (2 * C_) + h * HD_ + d0);
        uint4 wk1 = *(const uint4*)(kv + (size_t)(k0 + kr) * (2 * C_) + h * HD_ + d0 + 8);
        uint4 wv0 = *(const uint4*)(kv + (size_t)(k0 + kr) * (2 * C_) + C_ + h * HD_ + d0);
        uint4 wv1 = *(const uint4*)(kv + (size_t)(k0 + kr) * (2 * C_) + C_ + h * HD_ + d0 + 8);
        int mk[4];
#pragma unroll
        for (int j = 0; j < 4; j++) mk[j] = mask[k0 + tx * 4 + j];

        __syncthreads();  // prev iteration's PV reads of Ps/Vs done

        {   // K transposed into Ks[d][k]
            float f[8];
            unpack8(wk0, f);
#pragma unroll
            for (int v = 0; v < 8; v++) Ks[d0 + v][kr] = f[v];
            unpack8(wk1, f);
#pragma unroll
            for (int v = 0; v < 8; v++) Ks[d0 + 8 + v][kr] = f[v];
            // V natural into Vs[k][d] (float4 writes, 16B-aligned: pad=68)
            float g0[8], g1[8];
            unpack8(wv0, g0);
            unpack8(wv1, g1);
            *(float4*)&Vs[kr][d0]      = make_float4(g0[0], g0[1], g0[2], g0[3]);
            *(float4*)&Vs[kr][d0 + 4]  = make_float4(g0[4], g0[5], g0[6], g0[7]);
            *(float4*)&Vs[kr][d0 + 8]  = make_float4(g1[0], g1[1], g1[2], g1[3]);
            *(float4*)&Vs[kr][d0 + 12] = make_float4(g1[4], g1[5], g1[6], g1[7]);
        }
        __syncthreads();  // Ks/Vs ready

        // --- S = Q K^T tile (4x4 per thread) ---
        float s[4][4] = {};
#pragma unroll 8
        for (int d = 0; d < 64; d++) {
            float4 a = *(const float4*)&Qs[d][ty * 4];
            float4 b = *(const float4*)&Ks[d][tx * 4];
            float av[4] = {a.x, a.y, a.z, a.w};
            float bv[4] = {b.x, b.y, b.z, b.w};
#pragma unroll
            for (int i = 0; i < 4; i++)
#pragma unroll
                for (int j = 0; j < 4; j++)
                    s[i][j] = fmaf(av[i], bv[j], s[i][j]);
        }
        // scale + mask
#pragma unroll
        for (int i = 0; i < 4; i++)
#pragma unroll
            for (int j = 0; j < 4; j++)
                s[i][j] = mk[j] ? s[i][j] * scale : -1e30f;

        // --- online softmax row update (rows = ty*4+i, reduce across 16 tx lanes) ---
#pragma unroll
        for (int i = 0; i < 4; i++) {
            float mt = fmaxf(fmaxf(s[i][0], s[i][1]), fmaxf(s[i][2], s[i][3]));
#pragma unroll
            for (int o = 1; o < 16; o <<= 1) mt = fmaxf(mt, __shfl_xor(mt, o, 64));
            float nm = fmaxf(m_run[i], mt);
            float al = __expf(m_run[i] - nm);
            float rs = 0.f;
#pragma unroll
            for (int j = 0; j < 4; j++) {
                float p = __expf(s[i][j] - nm);
                s[i][j] = p;
                rs += p;
            }
#pragma unroll
            for (int o = 1; o < 16; o <<= 1) rs += __shfl_xor(rs, o, 64);
            l_run[i] = l_run[i] * al + rs;
            m_run[i] = nm;
#pragma unroll
            for (int j = 0; j < 4; j++) o_acc[i][j] *= al;
            // write P transposed: Ps[k][q]
#pragma unroll
            for (int j = 0; j < 4; j++) Ps[tx * 4 + j][ty * 4 + i] = s[i][j];
        }
        __syncthreads();  // Ps ready

        // --- O += P V ---
#pragma unroll 8
        for (int k = 0; k < 64; k++) {
            float4 a = *(const float4*)&Ps[k][ty * 4];
            float4 b = *(const float4*)&Vs[k][tx * 4];
            float av[4] = {a.x, a.y, a.z, a.w};
            float bv[4] = {b.x, b.y, b.z, b.w};
#pragma unroll
            for (int i = 0; i < 4; i++)
#pragma unroll
                for (int j = 0; j < 4; j++)
                    o_acc[i][j] = fmaf(av[i], bv[j], o_acc[i][j]);
        }
    }

    // --- epilogue ---
#pragma unroll
    for (int i = 0; i < 4; i++) {
        float inv = 1.0f / l_run[i];
        bf16* dst = out + (size_t)(q0 + ty * 4 + i) * C_ + h * HD_ + tx * 4;
#pragma unroll
        for (int j = 0; j < 4; j++) dst[j] = __float2bfloat16(o_acc[i][j] * inv);
    }
}

// ---------------------------------------------------------------------------
extern "C" void kernel_launch(void* const* d_in, const int* in_sizes, int n_in,
                              void* d_out, int out_size, void* d_ws, size_t ws_size,
                              hipStream_t stream)
{
    const void* query   = d_in[0];
    const void* context = d_in[1];
    const int*  mask    = (const int*)d_in[2];
    const void* Wqp = d_in[3];  const void* bqp  = d_in[4];
    const void* Wcp = d_in[5];  const void* bcp  = d_in[6];
    const void* Wq  = d_in[7];  const void* bq   = d_in[8];
    const void* Wkv = d_in[9];  const void* bkv  = d_in[10];
    const void* Wo  = d_in[11]; const void* bo   = d_in[12];
    const void* g1  = d_in[13]; const void* be1  = d_in[14];
    const void* W1  = d_in[15]; const void* bf1  = d_in[16];
    const void* W2  = d_in[17]; const void* bf2  = d_in[18];
    const void* g2  = d_in[19]; const void* be2  = d_in[20];
    const void* gf  = d_in[21]; const void* bef  = d_in[22];

    // workspace — peak 28 MB + 4 B flag (proven safe)
    char* w = (char*)d_ws;
    float* q   = (float*)(w);                 // [2048,1024] f32  8 MB @ 0
    bf16*  xn  = (bf16*) (w + ( 8u << 20));   // [2048,1024] bf16 4 MB @ 8
    bf16*  cb  = (bf16*) (w + ( 8u << 20));   // aliases xn (attention phase)
    bf16*  qh  = (bf16*) (w + (12u << 20));   // 4 MB @ 12
    bf16*  ao  = (bf16*) (w + (16u << 20));   // 4 MB @ 16
    bf16*  kvb = (bf16*) (w + (20u << 20));   // [2048,2048] bf16 8 MB @ 20
    bf16*  ff1 = (bf16*) (w + (12u << 20));   // [2048,4096] bf16 16 MB @ 12 (alias)
    int*   dtf = (int*)  (w + (28u << 20));   // dtype flag

    const int MQ = B_ * NQ_;   // 2048
    dim3 blk(256);

    sniff_k<<<1, blk, 0, stream>>>(query, dtf);

    gemm_k<0,0,1><<<dim3(C_/64, MQ/64), blk, 0, stream>>>(
        query, 0, Wqp, 0, bqp, 0, q, MQ, C_, DQ_, dtf);

    for (int l = 0; l < 2; l++) {
        const size_t oC  = (size_t)l * C_;
        const size_t oCC = (size_t)l * C_ * C_;
        const size_t o2C = (size_t)l * 2 * C_;
        const size_t oK2 = (size_t)l * C_ * 2 * C_;
        const size_t o4C = (size_t)l * 4 * C_;
        const size_t oK4 = (size_t)l * C_ * 4 * C_;

        ln_k<0><<<MQ, blk, 0, stream>>>(q, g1, be1, oC, xn, dtf);
        gemm_k<0,0,0><<<dim3(C_/64, MQ/64), blk, 0, stream>>>(
            xn, 0, Wq, oCC, bq, oC, qh, MQ, C_, C_, dtf);

        for (int b = 0; b < B_; b++) {
            gemm_k<0,0,1><<<dim3(C_/64, NC_/64), blk, 0, stream>>>(
                context, (size_t)b * NC_ * DC_, Wcp, 0, bcp, 0, cb, NC_, C_, DC_, dtf);
            gemm_k<0,0,0><<<dim3(2*C_/64, NC_/64), blk, 0, stream>>>(
                cb, 0, Wkv, oK2, bkv, o2C, kvb, NC_, 2*C_, C_, dtf);
            attn_flash<<<H_ * (NQ_/64), blk, 0, stream>>>(
                qh + (size_t)b * NQ_ * C_, kvb, mask + b * NC_, ao + (size_t)b * NQ_ * C_);
        }

        gemm_k<0,1,0><<<dim3(C_/64, MQ/64), blk, 0, stream>>>(
            ao, 0, Wo, oCC, bo, oC, q, MQ, C_, C_, dtf);
        ln_k<0><<<MQ, blk, 0, stream>>>(q, g2, be2, oC, xn, dtf);
        gemm_k<1,0,0><<<dim3(4*C_/64, MQ/64), blk, 0, stream>>>(
            xn, 0, W1, oK4, bf1, o4C, ff1, MQ, 4*C_, C_, dtf);
        gemm_k<0,1,0><<<dim3(C_/64, MQ/64), blk, 0, stream>>>(
            ff1, 0, W2, oK4, bf2, oC, q, MQ, C_, 4*C_, dtf);
    }

    ln_k<1><<<MQ, blk, 0, stream>>>(q, gf, bef, 0, d_out, dtf);
}

// Round 7
// 2824.642 us; speedup vs baseline: 5.4563x; 2.3914x over previous
//
#include <hip/hip_runtime.h>
#include <hip/hip_bf16.h>
#include <math.h>

typedef __hip_bfloat16 bf16;
using short8 = __attribute__((ext_vector_type(8))) short;
using f32x4  = __attribute__((ext_vector_type(4))) float;

#define B_    4
#define NQ_   512
#define NC_   2048
#define DQ_   1024
#define DC_   768
#define C_    1024
#define H_    16
#define HD_   64
#define EPS_  1e-5f

// ---- runtime-dtyped load of EXTERNAL tensors (flag: 1=fp32, 0=bf16) ----
__device__ __forceinline__ float ldin(const void* p, size_t i, int f32) {
    return f32 ? ((const float*)p)[i]
               : __bfloat162float(((const bf16*)p)[i]);
}
__device__ __forceinline__ unsigned bfb(float f) {
    return (unsigned)__builtin_bit_cast(unsigned short, __float2bfloat16(f));
}
// unpack 8 bf16 (as uint4) -> 8 fp32
__device__ __forceinline__ void unpack8(uint4 w, float* f) {
    f[0] = __uint_as_float((w.x & 0xffffu) << 16);
    f[1] = __uint_as_float(w.x & 0xffff0000u);
    f[2] = __uint_as_float((w.y & 0xffffu) << 16);
    f[3] = __uint_as_float(w.y & 0xffff0000u);
    f[4] = __uint_as_float((w.z & 0xffffu) << 16);
    f[5] = __uint_as_float(w.z & 0xffff0000u);
    f[6] = __uint_as_float((w.w & 0xffffu) << 16);
    f[7] = __uint_as_float(w.w & 0xffff0000u);
}

// ---------------------------------------------------------------------------
// dtype sniffer: flag[0] = (fp32 ? 1 : 0).
// ---------------------------------------------------------------------------
__global__ __launch_bounds__(256)
void sniff_k(const void* __restrict__ q, int* __restrict__ flag)
{
    __shared__ int red[256];
    const unsigned* w = (const unsigned*)q;
    const int t = threadIdx.x;
    int cnt = 0;
    for (int i = t; i < 1024; i += 256) {
        unsigned e = (w[i] >> 7) & 0xFFu;
        cnt += (e >= 0x70u && e <= 0x82u) ? 1 : 0;
    }
    red[t] = cnt; __syncthreads();
    for (int s = 128; s > 0; s >>= 1) { if (t < s) red[t] += red[t + s]; __syncthreads(); }
    if (t == 0) flag[0] = (red[0] > 512) ? 0 : 1;
}

// ---------------------------------------------------------------------------
// Transpose: dst[N][K] bf16 = src[off + k*ld + n] (runtime dtype).
// Grid (N/64, K/64), 256 threads, LDS 64x65 tile. Coverage: 256*16 = 64*64. OK
// ---------------------------------------------------------------------------
__global__ __launch_bounds__(256)
void tr_k(const void* __restrict__ src, size_t off, int ld,
          bf16* __restrict__ dst, int K, int N, const int* __restrict__ dtf)
{
    __shared__ short T[64 * 65];
    const int f32 = dtf[0];
    const int t = threadIdx.x;
    const int k0 = blockIdx.y * 64, n0 = blockIdx.x * 64;
    {
        const int k = t >> 2, nq = (t & 3) * 16;
        size_t si = off + (size_t)(k0 + k) * ld + n0 + nq;
        short v[16];
        if (f32) {
            const float* s = (const float*)src + si;
#pragma unroll
            for (int u = 0; u < 4; u++) {
                float4 f = *(const float4*)(s + u * 4);
                v[u*4+0] = (short)bfb(f.x); v[u*4+1] = (short)bfb(f.y);
                v[u*4+2] = (short)bfb(f.z); v[u*4+3] = (short)bfb(f.w);
            }
        } else {
            const bf16* s = (const bf16*)src + si;
#pragma unroll
            for (int u = 0; u < 2; u++) {
                uint4 x = *(const uint4*)(s + u * 8);
                unsigned a[4] = {x.x, x.y, x.z, x.w};
#pragma unroll
                for (int m = 0; m < 4; m++) {
                    v[u*8 + m*2]     = (short)(a[m] & 0xffffu);
                    v[u*8 + m*2 + 1] = (short)(a[m] >> 16);
                }
            }
        }
#pragma unroll
        for (int j = 0; j < 16; j++) T[k * 65 + nq + j] = v[j];
    }
    __syncthreads();
    {
        const int n = t >> 2, kq = (t & 3) * 16;
        unsigned pk[8];
#pragma unroll
        for (int u = 0; u < 8; u++) {
            unsigned lo = (unsigned short)T[(kq + u*2)     * 65 + n];
            unsigned hi = (unsigned short)T[(kq + u*2 + 1) * 65 + n];
            pk[u] = lo | (hi << 16);
        }
        bf16* d = dst + (size_t)(n0 + n) * K + k0 + kq;
        *(uint4*)(d)     = make_uint4(pk[0], pk[1], pk[2], pk[3]);
        *(uint4*)(d + 8) = make_uint4(pk[4], pk[5], pk[6], pk[7]);
    }
}

// ---------------------------------------------------------------------------
// MFMA GEMM: out[M,N] = act(A[M,K] @ Wt[N,K]^T + bscale*bias) (+= if ACC)
// 128x128 tile, BK=32, 256 thr / 4 waves, 16x16x32_bf16, fp32 acc.
// Staging: 2 threads/row, EACH stages 16 shorts (2x uint4) -> full 32-k cover.
// ---------------------------------------------------------------------------
template<int ACT, int ACC, int AEXT, int OUTF32>
__global__ __launch_bounds__(256)
void gemm_mfma(const void* __restrict__ A, size_t aoff, int lda,
               const bf16* __restrict__ Wt,
               const void* __restrict__ bias, size_t boff, float bscale,
               void* __restrict__ outp, int M, int N, int K,
               const int* __restrict__ dtf)
{
    __shared__ short As[128 * 40];   // [m][k], stride 40 (80 B, 16B-aligned)
    __shared__ short Bs[128 * 40];   // [n][k]
    const int f32 = AEXT ? dtf[0] : 0;
    const int t  = threadIdx.x;
    const int row0 = blockIdx.y * 128, col0 = blockIdx.x * 128;
    const int l  = t & 63, w = t >> 6;
    const int wr = (w >> 1) * 64, wc = (w & 1) * 64;
    const int lm = l & 15, lq = l >> 4, lk = lq * 8;
    const int sr = t >> 1, sh = (t & 1) * 16;    // staging: row, 16-short half

    f32x4 acc[4][4];
#pragma unroll
    for (int i = 0; i < 4; i++)
#pragma unroll
        for (int j = 0; j < 4; j++) { acc[i][j][0]=0.f; acc[i][j][1]=0.f; acc[i][j][2]=0.f; acc[i][j][3]=0.f; }

    for (int k0 = 0; k0 < K; k0 += 32) {
        uint4 a0, a1, b0, b1;
        if (AEXT && f32) {
            const float* Af = (const float*)A + aoff + (size_t)(row0 + sr) * lda + k0 + sh;
            float4 f0 = *(const float4*)(Af);
            float4 f1 = *(const float4*)(Af + 4);
            float4 f2 = *(const float4*)(Af + 8);
            float4 f3 = *(const float4*)(Af + 12);
            a0.x = bfb(f0.x) | (bfb(f0.y) << 16);
            a0.y = bfb(f0.z) | (bfb(f0.w) << 16);
            a0.z = bfb(f1.x) | (bfb(f1.y) << 16);
            a0.w = bfb(f1.z) | (bfb(f1.w) << 16);
            a1.x = bfb(f2.x) | (bfb(f2.y) << 16);
            a1.y = bfb(f2.z) | (bfb(f2.w) << 16);
            a1.z = bfb(f3.x) | (bfb(f3.y) << 16);
            a1.w = bfb(f3.z) | (bfb(f3.w) << 16);
        } else {
            const bf16* Ap = (const bf16*)A + aoff + (size_t)(row0 + sr) * lda + k0 + sh;
            a0 = *(const uint4*)(Ap);
            a1 = *(const uint4*)(Ap + 8);
        }
        {
            const bf16* Bp = Wt + (size_t)(col0 + sr) * K + k0 + sh;
            b0 = *(const uint4*)(Bp);
            b1 = *(const uint4*)(Bp + 8);
        }
        __syncthreads();
        *(uint4*)&As[sr * 40 + sh]     = a0;
        *(uint4*)&As[sr * 40 + sh + 8] = a1;
        *(uint4*)&Bs[sr * 40 + sh]     = b0;
        *(uint4*)&Bs[sr * 40 + sh + 8] = b1;
        __syncthreads();
        short8 af[4], bfr[4];
#pragma unroll
        for (int i = 0; i < 4; i++) af[i]  = *(const short8*)&As[(wr + i*16 + lm) * 40 + lk];
#pragma unroll
        for (int j = 0; j < 4; j++) bfr[j] = *(const short8*)&Bs[(wc + j*16 + lm) * 40 + lk];
#pragma unroll
        for (int i = 0; i < 4; i++)
#pragma unroll
            for (int j = 0; j < 4; j++)
                acc[i][j] = __builtin_amdgcn_mfma_f32_16x16x32_bf16(af[i], bfr[j], acc[i][j], 0, 0, 0);
    }

    const int fb = dtf[0];
#pragma unroll
    for (int i = 0; i < 4; i++) {
#pragma unroll
        for (int j = 0; j < 4; j++) {
            const int cgl = col0 + wc + j * 16 + lm;
            const float bsv = bscale * ldin(bias, boff + cgl, fb);
#pragma unroll
            for (int r = 0; r < 4; r++) {
                const int rgl = row0 + wr + i * 16 + lq * 4 + r;
                float v = acc[i][j][r] + bsv;
                if (ACT == 1) v = 0.5f * v * (1.0f + erff(v * 0.70710678118654752440f));
                size_t o = (size_t)rgl * N + cgl;
                if constexpr (ACC)          ((float*)outp)[o] += v;
                else if constexpr (OUTF32)  ((float*)outp)[o] = v;
                else                        ((bf16*)outp)[o] = __float2bfloat16(v);
            }
        }
    }
}

// ---------------------------------------------------------------------------
// LayerNorm (C_=1024). x fp32 ws. g/b external. OFINAL: d_out runtime dtype.
// ---------------------------------------------------------------------------
template<int OFINAL>
__global__ __launch_bounds__(256)
void ln_k(const float* __restrict__ x, const void* __restrict__ g,
          const void* __restrict__ b, size_t gboff, void* __restrict__ out,
          const int* __restrict__ dtf)
{
    __shared__ float red[256];
    const int f32 = dtf[0];
    const int row = blockIdx.x;
    const int t = threadIdx.x;
    const float* xr = x + (size_t)row * C_;
    float v[4];
#pragma unroll
    for (int i = 0; i < 4; i++) v[i] = xr[t + 256 * i];
    float s = v[0] + v[1] + v[2] + v[3];
    red[t] = s; __syncthreads();
    for (int st = 128; st > 0; st >>= 1) { if (t < st) red[t] += red[t + st]; __syncthreads(); }
    float mean = red[0] * (1.0f / C_);
    __syncthreads();
    float s2 = 0.f;
#pragma unroll
    for (int i = 0; i < 4; i++) { float d = v[i] - mean; s2 += d * d; }
    red[t] = s2; __syncthreads();
    for (int st = 128; st > 0; st >>= 1) { if (t < st) red[t] += red[t + st]; __syncthreads(); }
    float rstd = rsqrtf(red[0] * (1.0f / C_) + EPS_);
#pragma unroll
    for (int i = 0; i < 4; i++) {
        int cc = t + 256 * i;
        float r = (v[i] - mean) * rstd * ldin(g, gboff + cc, f32) + ldin(b, gboff + cc, f32);
        size_t o = (size_t)row * C_ + cc;
        if constexpr (OFINAL) {
            if (f32) ((float*)out)[o] = r; else ((bf16*)out)[o] = __float2bfloat16(r);
        } else {
            ((bf16*)out)[o] = __float2bfloat16(r);
        }
    }
}

// ---------------------------------------------------------------------------
// Flash attention (one batch element), IN-PLACE safe (disjoint per-block slices).
// ---------------------------------------------------------------------------
__global__ __launch_bounds__(256)
void attn_flash(const bf16* __restrict__ qh, const bf16* __restrict__ kv,
                const int* __restrict__ mask, bf16* __restrict__ out)
{
    __shared__ float Qs[64][68];
    __shared__ float Ks[64][68];
    __shared__ float Vs[64][68];
    __shared__ float Ps[64][68];
    const int h  = blockIdx.x >> 3;
    const int q0 = (blockIdx.x & 7) * 64;
    const int t  = threadIdx.x;
    const int tx = t & 15, ty = t >> 4;

    {
        const int qr = t >> 2, d0 = (t & 3) * 16;
        const bf16* src = qh + (size_t)(q0 + qr) * C_ + h * HD_ + d0;
        float f[8];
#pragma unroll
        for (int u = 0; u < 2; u++) {
            uint4 w = *(const uint4*)(src + u * 8);
            unpack8(w, f);
#pragma unroll
            for (int v = 0; v < 8; v++) Qs[d0 + u * 8 + v][qr] = f[v];
        }
    }

    float o_acc[4][4] = {};
    float m_run[4], l_run[4];
#pragma unroll
    for (int i = 0; i < 4; i++) { m_run[i] = -1e30f; l_run[i] = 0.f; }

    const float scale = 0.125f;

    for (int k0 = 0; k0 < NC_; k0 += 64) {
        const int kr = t >> 2, d0 = (t & 3) * 16;
        uint4 wk0 = *(const uint4*)(kv + (size_t)(k0 + kr) * (2 * C_) + h * HD_ + d0);
        uint4 wk1 = *(const uint4*)(kv + (size_t)(k0 + kr) * (2 * C_) + h * HD_ + d0 + 8);
        uint4 wv0 = *(const uint4*)(kv + (size_t)(k0 + kr) * (2 * C_) + C_ + h * HD_ + d0);
        uint4 wv1 = *(const uint4*)(kv + (size_t)(k0 + kr) * (2 * C_) + C_ + h * HD_ + d0 + 8);
        int mk[4];
#pragma unroll
        for (int j = 0; j < 4; j++) mk[j] = mask[k0 + tx * 4 + j];

        __syncthreads();

        {
            float f[8];
            unpack8(wk0, f);
#pragma unroll
            for (int v = 0; v < 8; v++) Ks[d0 + v][kr] = f[v];
            unpack8(wk1, f);
#pragma unroll
            for (int v = 0; v < 8; v++) Ks[d0 + 8 + v][kr] = f[v];
            float g0[8], g1[8];
            unpack8(wv0, g0);
            unpack8(wv1, g1);
            *(float4*)&Vs[kr][d0]      = make_float4(g0[0], g0[1], g0[2], g0[3]);
            *(float4*)&Vs[kr][d0 + 4]  = make_float4(g0[4], g0[5], g0[6], g0[7]);
            *(float4*)&Vs[kr][d0 + 8]  = make_float4(g1[0], g1[1], g1[2], g1[3]);
            *(float4*)&Vs[kr][d0 + 12] = make_float4(g1[4], g1[5], g1[6], g1[7]);
        }
        __syncthreads();

        float s[4][4] = {};
#pragma unroll 8
        for (int d = 0; d < 64; d++) {
            float4 a = *(const float4*)&Qs[d][ty * 4];
            float4 b = *(const float4*)&Ks[d][tx * 4];
            float av[4] = {a.x, a.y, a.z, a.w};
            float bv[4] = {b.x, b.y, b.z, b.w};
#pragma unroll
            for (int i = 0; i < 4; i++)
#pragma unroll
                for (int j = 0; j < 4; j++)
                    s[i][j] = fmaf(av[i], bv[j], s[i][j]);
        }
#pragma unroll
        for (int i = 0; i < 4; i++)
#pragma unroll
            for (int j = 0; j < 4; j++)
                s[i][j] = mk[j] ? s[i][j] * scale : -1e30f;

#pragma unroll
        for (int i = 0; i < 4; i++) {
            float mt = fmaxf(fmaxf(s[i][0], s[i][1]), fmaxf(s[i][2], s[i][3]));
#pragma unroll
            for (int o = 1; o < 16; o <<= 1) mt = fmaxf(mt, __shfl_xor(mt, o, 64));
            float nm = fmaxf(m_run[i], mt);
            float al = __expf(m_run[i] - nm);
            float rs = 0.f;
#pragma unroll
            for (int j = 0; j < 4; j++) {
                float p = __expf(s[i][j] - nm);
                s[i][j] = p;
                rs += p;
            }
#pragma unroll
            for (int o = 1; o < 16; o <<= 1) rs += __shfl_xor(rs, o, 64);
            l_run[i] = l_run[i] * al + rs;
            m_run[i] = nm;
#pragma unroll
            for (int j = 0; j < 4; j++) o_acc[i][j] *= al;
#pragma unroll
            for (int j = 0; j < 4; j++) Ps[tx * 4 + j][ty * 4 + i] = s[i][j];
        }
        __syncthreads();

#pragma unroll 8
        for (int k = 0; k < 64; k++) {
            float4 a = *(const float4*)&Ps[k][ty * 4];
            float4 b = *(const float4*)&Vs[k][tx * 4];
            float av[4] = {a.x, a.y, a.z, a.w};
            float bv[4] = {b.x, b.y, b.z, b.w};
#pragma unroll
            for (int i = 0; i < 4; i++)
#pragma unroll
                for (int j = 0; j < 4; j++)
                    o_acc[i][j] = fmaf(av[i], bv[j], o_acc[i][j]);
        }
    }

#pragma unroll
    for (int i = 0; i < 4; i++) {
        float inv = 1.0f / l_run[i];
        bf16* dst = out + (size_t)(q0 + ty * 4 + i) * C_ + h * HD_ + tx * 4;
#pragma unroll
        for (int j = 0; j < 4; j++) dst[j] = __float2bfloat16(o_acc[i][j] * inv);
    }
}

// ---------------------------------------------------------------------------
extern "C" void kernel_launch(void* const* d_in, const int* in_sizes, int n_in,
                              void* d_out, int out_size, void* d_ws, size_t ws_size,
                              hipStream_t stream)
{
    const void* query   = d_in[0];
    const void* context = d_in[1];
    const int*  mask    = (const int*)d_in[2];
    const void* Wqp = d_in[3];  const void* bqp  = d_in[4];
    const void* Wcp = d_in[5];  const void* bcp  = d_in[6];
    const void* Wq  = d_in[7];  const void* bq   = d_in[8];
    const void* Wkv = d_in[9];  const void* bkv  = d_in[10];
    const void* Wo  = d_in[11]; const void* bo   = d_in[12];
    const void* g1  = d_in[13]; const void* be1  = d_in[14];
    const void* W1  = d_in[15]; const void* bf1  = d_in[16];
    const void* W2  = d_in[17]; const void* bf2  = d_in[18];
    const void* g2  = d_in[19]; const void* be2  = d_in[20];
    const void* gf  = d_in[21]; const void* bef  = d_in[22];

    // workspace — peak 28 MB + 4 B (proven safe)
    char* w = (char*)d_ws;
    float* q    = (float*)(w);                 //  0- 8 residual f32
    bf16*  xn   = (bf16*) (w + ( 8u << 20));   //  8-12 LN out
    bf16*  cb   = (bf16*) (w + ( 8u << 20));   //  alias (attention phase)
    bf16*  qh   = (bf16*) (w + (12u << 20));   // 12-16 Q-heads / attn out (in-place)
    bf16*  ff1h = (bf16*) (w + (12u << 20));   // 12-20 MLP half (alias qh + kvb-low)
    bf16*  kvb  = (bf16*) (w + (16u << 20));   // 16-24 KV per batch
    bf16*  Wt   = (bf16*) (w + (24u << 20));   // 24-28 transposed weight slot
    int*   dtf  = (int*)  (w + (28u << 20));   // dtype flag

    const int MQ = B_ * NQ_;   // 2048
    dim3 blk(256);

    sniff_k<<<1, blk, 0, stream>>>(query, dtf);

    // q = query @ Wqp + bqp (f32)
    tr_k<<<dim3(C_/64, DQ_/64), blk, 0, stream>>>(Wqp, 0, C_, Wt, DQ_, C_, dtf);
    gemm_mfma<0,0,1,1><<<dim3(C_/128, MQ/128), blk, 0, stream>>>(
        query, 0, DQ_, Wt, bqp, 0, 1.f, q, MQ, C_, DQ_, dtf);

    for (int l = 0; l < 2; l++) {
        const size_t oC  = (size_t)l * C_;
        const size_t oCC = (size_t)l * C_ * C_;
        const size_t o2C = (size_t)l * 2 * C_;
        const size_t oK2 = (size_t)l * C_ * 2 * C_;
        const size_t o4C = (size_t)l * 4 * C_;
        const size_t oK4 = (size_t)l * C_ * 4 * C_;

        // LN1 -> xn ; qh = xn @ Wq + bq
        ln_k<0><<<MQ, blk, 0, stream>>>(q, g1, be1, oC, xn, dtf);
        tr_k<<<dim3(C_/64, C_/64), blk, 0, stream>>>(Wq, oCC, C_, Wt, C_, C_, dtf);
        gemm_mfma<0,0,0,0><<<dim3(C_/128, MQ/128), blk, 0, stream>>>(
            xn, 0, C_, Wt, bq, oC, 1.f, qh, MQ, C_, C_, dtf);

        for (int b = 0; b < B_; b++) {
            // cb = context_b @ Wcp + bcp
            tr_k<<<dim3(C_/64, DC_/64), blk, 0, stream>>>(Wcp, 0, C_, Wt, DC_, C_, dtf);
            gemm_mfma<0,0,1,0><<<dim3(C_/128, NC_/128), blk, 0, stream>>>(
                context, (size_t)b * NC_ * DC_, DC_, Wt, bcp, 0, 1.f, cb, NC_, C_, DC_, dtf);
            // kvb = cb @ Wkv + bkv
            tr_k<<<dim3(2*C_/64, C_/64), blk, 0, stream>>>(Wkv, oK2, 2*C_, Wt, C_, 2*C_, dtf);
            gemm_mfma<0,0,0,0><<<dim3(2*C_/128, NC_/128), blk, 0, stream>>>(
                cb, 0, C_, Wt, bkv, o2C, 1.f, kvb, NC_, 2*C_, C_, dtf);
            // attention, in-place on qh slice of batch b
            bf16* qh_b = qh + (size_t)b * NQ_ * C_;
            attn_flash<<<H_ * (NQ_/64), blk, 0, stream>>>(qh_b, kvb, mask + b * NC_, qh_b);
        }

        // q += qh @ Wo + bo
        tr_k<<<dim3(C_/64, C_/64), blk, 0, stream>>>(Wo, oCC, C_, Wt, C_, C_, dtf);
        gemm_mfma<0,1,0,1><<<dim3(C_/128, MQ/128), blk, 0, stream>>>(
            qh, 0, C_, Wt, bo, oC, 1.f, q, MQ, C_, C_, dtf);

        // LN2 -> xn ; MLP in two N/K halves
        ln_k<0><<<MQ, blk, 0, stream>>>(q, g2, be2, oC, xn, dtf);
        for (int hf = 0; hf < 2; hf++) {
            const size_t w1off = oK4 + (size_t)hf * 2048;             // col slice of W1 [C,4C]
            const size_t w2off = oK4 + (size_t)hf * 2048 * C_;        // row slice of W2 [4C,C]
            tr_k<<<dim3(2048/64, C_/64), blk, 0, stream>>>(W1, w1off, 4*C_, Wt, C_, 2048, dtf);
            gemm_mfma<1,0,0,0><<<dim3(2048/128, MQ/128), blk, 0, stream>>>(
                xn, 0, C_, Wt, bf1, o4C + hf * 2048, 1.f, ff1h, MQ, 2048, C_, dtf);
            tr_k<<<dim3(C_/64, 2048/64), blk, 0, stream>>>(W2, w2off, C_, Wt, 2048, C_, dtf);
            gemm_mfma<0,1,0,1><<<dim3(C_/128, MQ/128), blk, 0, stream>>>(
                ff1h, 0, 2048, Wt, bf2, oC, (hf == 0) ? 1.f : 0.f, q, MQ, C_, 2048, dtf);
        }
    }

    ln_k<1><<<MQ, blk, 0, stream>>>(q, gf, bef, 0, d_out, dtf);
}